// Round 2
// baseline (697.841 us; speedup 1.0000x reference)
//
#include <hip/hip_runtime.h>
#include <hip/hip_bf16.h>

// y[t,o] = sum_i x[t,i] * ((w_pos[o,i]>0) - (w_neg[o,i]>0))
// M=8192, N=4096, K=4096, f32 in/out.
// W_eff in {-1,0,1} exact in f16; x -> f16 (rel err 2^-11, output err ~6e-5
// of absmax); single f16 MFMA GEMM, m97 structure (128x128, BK=64, 4 waves).

#define M_DIM 8192
#define N_DIM 4096
#define K_DIM 4096

#define BM 128
#define BN 128
#define BK 64

typedef __attribute__((ext_vector_type(4))) float f32x4;
typedef __attribute__((ext_vector_type(8))) _Float16 f16x8;
typedef __attribute__((ext_vector_type(8))) unsigned short u16x8;

__device__ __forceinline__ void async_copy16(const void* gptr, const ushort* ldsptr) {
    __builtin_amdgcn_global_load_lds(
        (const __attribute__((address_space(1))) unsigned int*)gptr,
        (__attribute__((address_space(3))) unsigned int*)ldsptr,
        16, 0, 0);
}

// ---------------- pre-pass: W_eff = (wp>0) - (wn>0) as f16 bits ------------
__global__ __launch_bounds__(256) void convert_w(const float* __restrict__ wp,
                                                 const float* __restrict__ wn,
                                                 ushort* __restrict__ W) {
    long idx = (long)blockIdx.x * 256 + threadIdx.x;  // 8 elems / thread
    const float4* wp4 = (const float4*)wp;
    const float4* wn4 = (const float4*)wn;
    float4 p0 = wp4[idx * 2], p1 = wp4[idx * 2 + 1];
    float4 n0 = wn4[idx * 2], n1 = wn4[idx * 2 + 1];
    float pv[8] = {p0.x, p0.y, p0.z, p0.w, p1.x, p1.y, p1.z, p1.w};
    float nv[8] = {n0.x, n0.y, n0.z, n0.w, n1.x, n1.y, n1.z, n1.w};
    u16x8 o;
#pragma unroll
    for (int j = 0; j < 8; ++j) {
        int t = (pv[j] > 0.0f) - (nv[j] > 0.0f);
        o[j] = (t == 0) ? 0 : (t > 0 ? 0x3C00 : 0xBC00);  // f16 {0,+1,-1}
    }
    *(u16x8*)(W + idx * 8) = o;
}

// ---------------- pre-pass: A = f16(x) -------------------------------------
__global__ __launch_bounds__(256) void convert_x(const float* __restrict__ x,
                                                 ushort* __restrict__ A) {
    long idx = (long)blockIdx.x * 256 + threadIdx.x;  // 8 elems / thread
    const float4* x4 = (const float4*)x;
    float4 v0 = x4[idx * 2], v1 = x4[idx * 2 + 1];
    float xv[8] = {v0.x, v0.y, v0.z, v0.w, v1.x, v1.y, v1.z, v1.w};
    u16x8 o;
#pragma unroll
    for (int j = 0; j < 8; ++j) {
        _Float16 h = (_Float16)xv[j];               // RN f32->f16
        o[j] = *(unsigned short*)&h;
    }
    *(u16x8*)(A + idx * 8) = o;
}

// ---------------- main GEMM: C[MxN] = A[MxK] * W^T --------------------------
// W stored [N][K] row-major (B^T input). m97 structure: 128x128 tile, BK=64,
// 4 waves (2x2), 16x16x32 f16 MFMA, global_load_lds w=16, 2 barriers/K-step.
__global__ __launch_bounds__(256) void gemm_bt(const ushort* __restrict__ A,
                                               const ushort* __restrict__ B,
                                               float* __restrict__ C) {
    __shared__ __align__(16) ushort ldsbuf[BM * BK + BN * BK];  // 32 KiB

    const int tid  = threadIdx.x;
    const int lane = tid & 63;
    const int w    = tid >> 6;     // wave 0..3
    const int wr   = w >> 1;       // wave row 0..1
    const int wc   = w & 1;        // wave col 0..1

    // bijective XCD swizzle (2048 blocks, 2048 % 8 == 0)
    const int bid = blockIdx.x;
    const int wg  = (bid & 7) * 256 + (bid >> 3);
    const int bm  = wg >> 5;   // / (N/BN = 32)
    const int bn  = wg & 31;

    // staging: 32 KiB / (256 thr * 16 B) = 8 loads/thread.
    // chunk c (0..15): 8 rows; lane l -> row c*8+(l>>3), colbyte (l&7)*16;
    // LDS linear offset c*1024 + l*16 matches HW (base + lane*16).
    const int srow  = lane >> 3;
    const int scolb = (lane & 7) << 4;

    const char* aBase[4];
    const char* bBase[4];
    const ushort* ldsA[4];
    const ushort* ldsB[4];
#pragma unroll
    for (int i = 0; i < 4; ++i) {
        int c = w * 4 + i;  // this wave's chunks
        long arow = (long)bm * BM + c * 8 + srow;
        long brow = (long)bn * BN + c * 8 + srow;
        aBase[i] = (const char*)A + arow * (K_DIM * 2) + scolb;
        bBase[i] = (const char*)B + brow * (K_DIM * 2) + scolb;
        ldsA[i] = ldsbuf + c * 512;             // 1024 B per chunk
        ldsB[i] = ldsbuf + BM * BK + c * 512;
    }

    f32x4 acc[4][4] = {};

    const int r = lane & 15;   // A row in tile / C col
    const int q = lane >> 4;   // k-group / C row-group
    const ushort* lA = ldsbuf;
    const ushort* lB = ldsbuf + BM * BK;

    for (int kt = 0; kt < K_DIM / BK; ++kt) {
        __syncthreads();  // all waves done reading previous tile
        const int koff = kt * (BK * 2);   // byte offset along K
#pragma unroll
        for (int i = 0; i < 4; ++i) {
            async_copy16(aBase[i] + koff, ldsA[i]);
            async_copy16(bBase[i] + koff, ldsB[i]);
        }
        __syncthreads();  // staging complete (compiler drains vmcnt at barrier)

#pragma unroll
        for (int kk = 0; kk < 2; ++kk) {
            f16x8 af[4], bf[4];
#pragma unroll
            for (int m = 0; m < 4; ++m)
                af[m] = *(const f16x8*)(lA + (wr * 64 + m * 16 + r) * BK + kk * 32 + q * 8);
#pragma unroll
            for (int n = 0; n < 4; ++n)
                bf[n] = *(const f16x8*)(lB + (wc * 64 + n * 16 + r) * BK + kk * 32 + q * 8);
#pragma unroll
            for (int m = 0; m < 4; ++m)
#pragma unroll
                for (int n = 0; n < 4; ++n)
                    acc[m][n] = __builtin_amdgcn_mfma_f32_16x16x32_f16(
                        af[m], bf[n], acc[m][n], 0, 0, 0);
        }
    }

    // C/D layout (m89-verified, dtype-independent): col=lane&15, row=(lane>>4)*4+reg
    const long row0 = (long)bm * BM + wr * 64;
    const int  col0 = bn * BN + wc * 64;
#pragma unroll
    for (int m = 0; m < 4; ++m)
#pragma unroll
        for (int n = 0; n < 4; ++n)
#pragma unroll
            for (int j = 0; j < 4; ++j)
                C[(row0 + m * 16 + q * 4 + j) * N_DIM + col0 + n * 16 + r] =
                    acc[m][n][j];
}

// ---------------- correctness fallback (only if ws too small) --------------
__global__ __launch_bounds__(256) void fallback_gemm(const float* __restrict__ x,
                                                     const float* __restrict__ wp,
                                                     const float* __restrict__ wn,
                                                     float* __restrict__ out) {
    __shared__ float xs[K_DIM];
    const long t = blockIdx.y;
    const int  o = blockIdx.x * 256 + threadIdx.x;
    for (int i = threadIdx.x; i < K_DIM; i += 256) xs[i] = x[t * K_DIM + i];
    __syncthreads();
    const float* wpr = wp + (long)o * K_DIM;
    const float* wnr = wn + (long)o * K_DIM;
    float s = 0.0f;
    for (int i = 0; i < K_DIM; i += 4) {
        float4 p = *(const float4*)(wpr + i);
        float4 n = *(const float4*)(wnr + i);
        s += xs[i + 0] * (float)((p.x > 0.0f) - (n.x > 0.0f));
        s += xs[i + 1] * (float)((p.y > 0.0f) - (n.y > 0.0f));
        s += xs[i + 2] * (float)((p.z > 0.0f) - (n.z > 0.0f));
        s += xs[i + 3] * (float)((p.w > 0.0f) - (n.w > 0.0f));
    }
    out[t * N_DIM + o] = s;
}

extern "C" void kernel_launch(void* const* d_in, const int* in_sizes, int n_in,
                              void* d_out, int out_size, void* d_ws, size_t ws_size,
                              hipStream_t stream) {
    const float* x  = (const float*)d_in[0];
    const float* wp = (const float*)d_in[1];
    const float* wn = (const float*)d_in[2];
    float* out = (float*)d_out;

    const size_t wBytes = (size_t)N_DIM * K_DIM * sizeof(ushort);  // 33.5 MB
    const size_t aBytes = (size_t)M_DIM * K_DIM * sizeof(ushort);  // 67 MB

    if (ws_size >= wBytes + aBytes) {
        ushort* W = (ushort*)d_ws;
        ushort* A = (ushort*)((char*)d_ws + wBytes);
        convert_w<<<(N_DIM * K_DIM / 8) / 256, 256, 0, stream>>>(wp, wn, W);
        convert_x<<<(M_DIM * K_DIM / 8) / 256, 256, 0, stream>>>(x, A);
        gemm_bt<<<(M_DIM / BM) * (N_DIM / BN), 256, 0, stream>>>(A, W, out);
    } else {
        dim3 g(N_DIM / 256, M_DIM);
        fallback_gemm<<<g, 256, 0, stream>>>(x, wp, wn, out);
    }
}

// Round 6
// 521.426 us; speedup vs baseline: 1.3383x; 1.3383x over previous
//
#include <hip/hip_runtime.h>
#include <hip/hip_bf16.h>

// y[t,o] = sum_i x[t,i] * ((w_pos[o,i]>0) - (w_neg[o,i]>0))
// M=8192, N=4096, K=4096, f32 in/out.
// W_eff {-1,0,1} exact in f16; x -> f16; single f16 MFMA GEMM.
// GEMM (unchanged from r4 audit): 256x256 tile, BKT=32, 4-deep LDS ring,
// counted vmcnt(8) (T3+T4), row[2:1]->byte[5:4] XOR swizzle (T2, 2-way max
// for 64B rows), setprio (T5), 8 waves, bijective XCD swizzle (T1).
// Converts: single balanced grid-stride launch (2048 blocks).

#define M_DIM 8192
#define N_DIM 4096
#define K_DIM 4096
#define K2 (K_DIM * 2)      // global row stride in bytes (ushort K)

#define BM 256
#define BN 256
#define BKT 32
#define NT (K_DIM / BKT)    // 128 K-tiles

typedef __attribute__((ext_vector_type(4))) float f32x4;
typedef __attribute__((ext_vector_type(8))) _Float16 f16x8;
typedef __attribute__((ext_vector_type(8))) unsigned short u16x8;

__device__ __forceinline__ void async_copy16(const void* g, const ushort* l) {
    __builtin_amdgcn_global_load_lds(
        (const __attribute__((address_space(1))) unsigned int*)g,
        (__attribute__((address_space(3))) unsigned int*)l, 16, 0, 0);
}

// ------------- fused pre-pass: W_eff (f16 {-1,0,1}) and A = f16(x) ---------
// One combined grid-stride index space for perfect W/x load balance:
// idx < totalW -> W element-block, else x element-block (8 f32 per idx).
__global__ __launch_bounds__(256) void convert_all(const float* __restrict__ wp,
                                                   const float* __restrict__ wn,
                                                   const float* __restrict__ x,
                                                   ushort* __restrict__ W,
                                                   ushort* __restrict__ A) {
    const long totalW = (long)N_DIM * K_DIM / 8;
    const long total  = totalW + (long)M_DIM * K_DIM / 8;
    const long step   = (long)gridDim.x * 256;
    for (long idx = (long)blockIdx.x * 256 + threadIdx.x; idx < total; idx += step) {
        if (idx < totalW) {
            const float4* wp4 = (const float4*)wp;
            const float4* wn4 = (const float4*)wn;
            float4 p0 = wp4[idx * 2], p1 = wp4[idx * 2 + 1];
            float4 n0 = wn4[idx * 2], n1 = wn4[idx * 2 + 1];
            float pv[8] = {p0.x, p0.y, p0.z, p0.w, p1.x, p1.y, p1.z, p1.w};
            float nv[8] = {n0.x, n0.y, n0.z, n0.w, n1.x, n1.y, n1.z, n1.w};
            u16x8 o;
#pragma unroll
            for (int j = 0; j < 8; ++j) {
                int t = (pv[j] > 0.0f) - (nv[j] > 0.0f);
                o[j] = (t == 0) ? 0 : (t > 0 ? 0x3C00 : 0xBC00);  // f16 {0,+1,-1}
            }
            *(u16x8*)(W + idx * 8) = o;
        } else {
            const long xi = idx - totalW;
            const float4* x4 = (const float4*)x;
            float4 v0 = x4[xi * 2], v1 = x4[xi * 2 + 1];
            float xv[8] = {v0.x, v0.y, v0.z, v0.w, v1.x, v1.y, v1.z, v1.w};
            u16x8 o;
#pragma unroll
            for (int j = 0; j < 8; ++j) {
                _Float16 h = (_Float16)xv[j];   // RN f32->f16
                o[j] = *(unsigned short*)&h;
            }
            *(u16x8*)(A + xi * 8) = o;
        }
    }
}

// ---------------- main GEMM: C[MxN] = A[MxK] * W^T --------------------------
// LDS region per buf per matrix: 16 KiB = 256 rows x 64 B (32 f16 of K).
// Swizzle (involution): byte ^= ((row>>1)&3)<<4  (row bits [2:1] = byte bits
// [8:7] XOR into byte bits [5:4]). A b128 fragment read: quarter-group lane r
// starts at bank 4*(16(r&1) != wait -- see audit) = 16(r&1)+4(q^((r>>1)&3)):
// 8 distinct 16B slots x 2 lanes = 2-way (free, m136); whole wave lands
// exactly 8 accesses/bank = the 64-lane b128 floor.
// global_load_lds writes LINEAR dest; per-lane GLOBAL source pre-swizzled
// with the same XOR (rule #21); ds_read applies the XOR.
//
// Schedule: 4-deep ring (buf = t&3). While computing tile t: stage tile t+3.
// 4 gload_lds / wave / tile -> at TILE(t) entry outstanding = {t,t+1,t+2} =
// 12; vmcnt(8) retires exactly tile t; barrier certifies all waves' tile-t
// DMA landed; then read. Never drains to 0 in the main loop (T4).
// Epilogue: 8 -> 4 -> 0. WAR on buf (t+4)&3==t&3 is safe: stage issues after
// the TILE(t+1) barrier, and every wave's tile-t ds_reads retired (lgkmcnt
// waits precede its TILE(t) MFMAs, which precede that barrier).
#define TILE(tt, VMC, DOSTAGE)                                                 \
    {                                                                          \
        asm volatile("s_waitcnt vmcnt(" #VMC ")" ::: "memory");                \
        __builtin_amdgcn_s_barrier();                                          \
        asm volatile("" ::: "memory");                                         \
        ushort* la = lds + ((tt) & 3) * 16384;                                 \
        ushort* lb = la + 8192;                                                \
        if (DOSTAGE) {                                                         \
            ushort* ld = lds + (((tt) + 3) & 3) * 16384;                       \
            const char* as = Aptr + (long)((tt) + 3) * 64;                     \
            const char* bs = Bptr + (long)((tt) + 3) * 64;                     \
            async_copy16(as + gOff0, ld + (lB0 >> 1));                         \
            async_copy16(as + gOff1, ld + (lB1 >> 1));                         \
            async_copy16(bs + gOff0, ld + 8192 + (lB0 >> 1));                  \
            async_copy16(bs + gOff1, ld + 8192 + (lB1 >> 1));                  \
        }                                                                      \
        f16x8 af[4], bfr[4];                                                   \
        _Pragma("unroll") for (int n = 0; n < 4; ++n)                          \
            bfr[n] = *(const f16x8*)(lb + bOffs[n]);                           \
        _Pragma("unroll") for (int m = 0; m < 4; ++m)                          \
            af[m] = *(const f16x8*)(la + aOffs[m]);                            \
        __builtin_amdgcn_s_setprio(1);                                         \
        _Pragma("unroll") for (int m = 0; m < 4; ++m)                          \
            _Pragma("unroll") for (int n = 0; n < 4; ++n)                      \
                acc[m][n] = __builtin_amdgcn_mfma_f32_16x16x32_f16(            \
                    af[m], bfr[n], acc[m][n], 0, 0, 0);                        \
        __builtin_amdgcn_s_setprio(0);                                         \
        _Pragma("unroll") for (int m = 0; m < 4; ++m)                          \
            af[m] = *(const f16x8*)(la + aOffs[4 + m]);                        \
        __builtin_amdgcn_s_setprio(1);                                         \
        _Pragma("unroll") for (int m = 0; m < 4; ++m)                          \
            _Pragma("unroll") for (int n = 0; n < 4; ++n)                      \
                acc[4 + m][n] = __builtin_amdgcn_mfma_f32_16x16x32_f16(        \
                    af[m], bfr[n], acc[4 + m][n], 0, 0, 0);                    \
        __builtin_amdgcn_s_setprio(0);                                         \
    }

__global__ __launch_bounds__(512, 2) void gemm_bt(const ushort* __restrict__ A,
                                                  const ushort* __restrict__ B,
                                                  float* __restrict__ C) {
    __shared__ __align__(16) ushort lds[65536];  // 128 KiB: 4 bufs x 32 KiB (A16K+B16K)

    const int tid  = threadIdx.x;
    const int lane = tid & 63;
    const int wv   = tid >> 6;   // 0..7
    const int wr   = wv >> 2;    // 0..1 : M-half (128 rows)
    const int wc   = wv & 3;     // 0..3 : N-quarter (64 cols)
    const int r    = lane & 15;
    const int q    = lane >> 4;

    // bijective XCD swizzle (512 blocks, 512 % 8 == 0, 64 blocks/XCD)
    const int bid = blockIdx.x;
    const int wg  = (bid & 7) * 64 + (bid >> 3);
    const int bm  = wg >> 4;     // 0..31
    const int bn  = wg & 15;     // 0..15

    // --- staging precompute ---
    // LDS linear byte L (within 16 KiB region): data(L) = logical element at
    // P = L ^ (((L>>7)&3)<<4); P = row*64 + byte-in-row.
    const int lB0 = (wv * 64) * 16;          // wave-uniform LDS dest, load 0
    const int lB1 = (512 + wv * 64) * 16;    // load 1 (+8 KiB)
    long gOff0, gOff1;
    {
        int L0 = lB0 + lane * 16;
        int L1 = lB1 + lane * 16;
        int P0 = L0 ^ (((L0 >> 7) & 3) << 4);
        int P1 = L1 ^ (((L1 >> 7) & 3) << 4);
        gOff0 = (long)(P0 >> 6) * K2 + (P0 & 63);
        gOff1 = (long)(P1 >> 6) * K2 + (P1 & 63);
    }
    const char* Aptr = (const char*)A + (long)bm * 256 * K2;
    const char* Bptr = (const char*)B + (long)bn * 256 * K2;

    // --- fragment ds_read offsets (swizzled), ushort units ---
    int aOffs[8], bOffs[4];
#pragma unroll
    for (int m = 0; m < 8; ++m) {
        int row  = wr * 128 + m * 16 + r;
        int byte = row * 64 + q * 16;
        byte ^= ((row >> 1) & 3) << 4;
        aOffs[m] = byte >> 1;
    }
#pragma unroll
    for (int n = 0; n < 4; ++n) {
        int row  = wc * 64 + n * 16 + r;
        int byte = row * 64 + q * 16;
        byte ^= ((row >> 1) & 3) << 4;
        bOffs[n] = byte >> 1;
    }

    f32x4 acc[8][4] = {};

    // --- prologue: stage tiles 0..2 into bufs 0..2 (12 loads in flight) ---
#pragma unroll
    for (int t = 0; t < 3; ++t) {
        ushort* la = lds + t * 16384;
        const char* as = Aptr + (long)t * 64;
        const char* bs = Bptr + (long)t * 64;
        async_copy16(as + gOff0, la + (lB0 >> 1));
        async_copy16(as + gOff1, la + (lB1 >> 1));
        async_copy16(bs + gOff0, la + 8192 + (lB0 >> 1));
        async_copy16(bs + gOff1, la + 8192 + (lB1 >> 1));
    }

    for (int t = 0; t < NT - 3; ++t) TILE(t, 8, true);
    TILE(NT - 3, 8, false);
    TILE(NT - 2, 4, false);
    TILE(NT - 1, 0, false);

    // C/D layout (verified round 2): col = lane&15, row = (lane>>4)*4 + reg
    const long row0 = (long)bm * 256 + wr * 128;
    const int  col0 = bn * 256 + wc * 64;
#pragma unroll
    for (int m = 0; m < 8; ++m)
#pragma unroll
        for (int n = 0; n < 4; ++n)
#pragma unroll
            for (int j = 0; j < 4; ++j)
                C[(row0 + m * 16 + q * 4 + j) * N_DIM + col0 + n * 16 + r] =
                    acc[m][n][j];
}

// ---------------- correctness fallback (only if ws too small) --------------
__global__ __launch_bounds__(256) void fallback_gemm(const float* __restrict__ x,
                                                     const float* __restrict__ wp,
                                                     const float* __restrict__ wn,
                                                     float* __restrict__ out) {
    __shared__ float xs[K_DIM];
    const long t = blockIdx.y;
    const int  o = blockIdx.x * 256 + threadIdx.x;
    for (int i = threadIdx.x; i < K_DIM; i += 256) xs[i] = x[t * K_DIM + i];
    __syncthreads();
    const float* wpr = wp + (long)o * K_DIM;
    const float* wnr = wn + (long)o * K_DIM;
    float s = 0.0f;
    for (int i = 0; i < K_DIM; i += 4) {
        float4 p = *(const float4*)(wpr + i);
        float4 n = *(const float4*)(wnr + i);
        s += xs[i + 0] * (float)((p.x > 0.0f) - (n.x > 0.0f));
        s += xs[i + 1] * (float)((p.y > 0.0f) - (n.y > 0.0f));
        s += xs[i + 2] * (float)((p.z > 0.0f) - (n.z > 0.0f));
        s += xs[i + 3] * (float)((p.w > 0.0f) - (n.w > 0.0f));
    }
    out[t * N_DIM + o] = s;
}

extern "C" void kernel_launch(void* const* d_in, const int* in_sizes, int n_in,
                              void* d_out, int out_size, void* d_ws, size_t ws_size,
                              hipStream_t stream) {
    const float* x  = (const float*)d_in[0];
    const float* wp = (const float*)d_in[1];
    const float* wn = (const float*)d_in[2];
    float* out = (float*)d_out;

    const size_t wBytes = (size_t)N_DIM * K_DIM * sizeof(ushort);  // 33.5 MB
    const size_t aBytes = (size_t)M_DIM * K_DIM * sizeof(ushort);  // 67 MB

    if (ws_size >= wBytes + aBytes) {
        ushort* W = (ushort*)d_ws;
        ushort* A = (ushort*)((char*)d_ws + wBytes);
        convert_all<<<2048, 256, 0, stream>>>(wp, wn, x, W, A);
        gemm_bt<<<(M_DIM / BM) * (N_DIM / BN), 512, 0, stream>>>(A, W, out);
    } else {
        dim3 g(N_DIM / 256, M_DIM);
        fallback_gemm<<<g, 256, 0, stream>>>(x, wp, wn, out);
    }
}